// Round 9
// baseline (61.366 us; speedup 1.0000x reference)
//
#include <hip/hip_runtime.h>

// Problem constants: N=131072, D=512, C=64, CHUNK=8
#define NC          8388608     // N * C
#define NCHUNK      16384       // N / 8
#define ALPHA       0.1f
#define FEAT_BLOCKS 2048        // 8192 waves, exactly 2 chunks per wave
#define MSE_BLOCKS  512         // exactly 16 float4 iters per thread
#define TOTAL_BLOCKS (FEAT_BLOCKS + MSE_BLOCKS)   // 2560 = 10 * 256
#define PART_OFF    32          // partials start 128 B into ws (counter at ws[0])

typedef float floatx4 __attribute__((ext_vector_type(4)));  // native vector for nt builtin

// Single v_add_f32 with DPP modifier (rocPRIM wave64 reduce pattern).
template<int ctrl, int rmask>
__device__ __forceinline__ float dpp_add(float v) {
    int t = __builtin_amdgcn_update_dpp(0, __float_as_int(v), ctrl, rmask, 0xf, true);
    return v + __int_as_float(t);
}

// Full 64-lane sum; result valid in lane 63.
__device__ __forceinline__ float wave_reduce_dpp(float v) {
    v = dpp_add<0xB1,  0xf>(v);  // quad_perm xor1
    v = dpp_add<0x4E,  0xf>(v);  // quad_perm xor2
    v = dpp_add<0x141, 0xf>(v);  // row_half_mirror
    v = dpp_add<0x140, 0xf>(v);  // row_mirror
    v = dpp_add<0x142, 0xa>(v);  // row_bcast:15
    v = dpp_add<0x143, 0xc>(v);  // row_bcast:31
    return v;
}

// Non-temporal 16B load: read-once streaming data, don't allocate in cache.
__device__ __forceinline__ floatx4 nt_load4(const float4* p) {
    return __builtin_nontemporal_load((const floatx4*)p);
}

__global__ __launch_bounds__(256) void fused_kernel(const float* __restrict__ feat,
                                                    const float* __restrict__ pred,
                                                    const float* __restrict__ tgt,
                                                    float* __restrict__ ws,
                                                    float* __restrict__ out) {
    const int lane = threadIdx.x & 63;
    const int wave = threadIdx.x >> 6;
    __shared__ float bsum[4];
    __shared__ int is_last;
    float* part = ws + PART_OFF;
    unsigned* counter = (unsigned*)ws;
    float block_val;

    if (blockIdx.x < FEAT_BLOCKS) {
        // ---- feat_dist: one wave per 8x512 chunk, exactly 2 chunks/wave ----
        const int wid = blockIdx.x * 4 + wave;
        float wacc = 0.f;                     // per-wave accumulator (lane 63)
        #pragma unroll
        for (int s = 0; s < 2; ++s) {
            const int chunk = wid + s * (FEAT_BLOCKS * 4);
            const float4* base = (const float4*)(feat + (size_t)chunk * 8 * 512);
            float a[8][8];
            #pragma unroll
            for (int i = 0; i < 8; ++i) {
                floatx4 v1 = nt_load4(base + i * 128 + lane);
                floatx4 v2 = nt_load4(base + i * 128 + 64 + lane);
                a[i][0] = v1.x; a[i][1] = v1.y; a[i][2] = v1.z; a[i][3] = v1.w;
                a[i][4] = v2.x; a[i][5] = v2.y; a[i][6] = v2.z; a[i][7] = v2.w;
            }

            // 36 upper-tri (incl. diag) per-lane partial dots.
            float p[36];
            #pragma unroll
            for (int i = 0; i < 8; ++i) {
                #pragma unroll
                for (int j = i; j < 8; ++j) {
                    const int idx = 8 * i - (i * (i - 1)) / 2 + (j - i);
                    float s2 = 0.f;
                    #pragma unroll
                    for (int k = 0; k < 8; ++k) s2 = fmaf(a[i][k], a[j][k], s2);
                    p[idx] = s2;
                }
            }

            // Cross-lane sum of all 36 partials, pure-VALU DPP.
            #pragma unroll
            for (int k = 0; k < 36; ++k) p[k] = wave_reduce_dpp(p[k]);

            if (lane == 63) {
                const int diag[8] = {0, 8, 15, 21, 26, 30, 33, 35};
                float rn[8];
                #pragma unroll
                for (int i = 0; i < 8; ++i) rn[i] = rsqrtf(p[diag[i]]);
                float acc = 0.f;
                #pragma unroll
                for (int i = 0; i < 8; ++i) {
                    #pragma unroll
                    for (int j = i + 1; j < 8; ++j) {
                        const int idx = 8 * i - (i * (i - 1)) / 2 + (j - i);
                        acc = fmaf(p[idx], rn[i] * rn[j], acc);
                    }
                }
                wacc += 28.0f - acc;          // sum of (1 - sim) over 28 pairs
            }
        }
        if (lane == 63) bsum[wave] = wacc;
        __syncthreads();
        block_val = ALPHA * ((bsum[0] + bsum[1]) + (bsum[2] + bsum[3]));
    } else {
        // ---- MSE over 8.4M elements: exactly 16 float4 iters per thread ----
        const int bid = blockIdx.x - FEAT_BLOCKS;
        const float4* p4 = (const float4*)pred;
        const float4* t4 = (const float4*)tgt;
        const int n4 = NC / 4;
        float s = 0.f;
        for (int i = bid * blockDim.x + threadIdx.x; i < n4;
             i += MSE_BLOCKS * blockDim.x) {
            floatx4 a = nt_load4(p4 + i);
            floatx4 b = nt_load4(t4 + i);
            float dx = a.x - b.x, dy = a.y - b.y, dz = a.z - b.z, dw = a.w - b.w;
            s += dx * dx + dy * dy + dz * dz + dw * dw;
        }
        s = wave_reduce_dpp(s);
        if (lane == 63) bsum[wave] = s;
        __syncthreads();
        block_val = ((bsum[0] + bsum[1]) + (bsum[2] + bsum[3])) * (1.0f / (float)NC);
    }

    // ---- fence-free last-block-done reduction ----
    // Relaxed AGENT-scope accesses set sc1 on the individual op (coherence-point
    // access) -- no buffer_wbl2/buffer_inv cache maintenance (R4's mistake).
    if (threadIdx.x == 0) {
        __hip_atomic_store(&part[blockIdx.x], block_val,
                           __ATOMIC_RELAXED, __HIP_MEMORY_SCOPE_AGENT);
        asm volatile("s_waitcnt vmcnt(0)" ::: "memory");  // wave-local drain, not a flush
        unsigned prev = __hip_atomic_fetch_add(counter, 1u, __ATOMIC_RELAXED,
                                               __HIP_MEMORY_SCOPE_AGENT);
        // Counter is never reset: any window of 2560 consecutive increments
        // contains exactly one multiple of 2560 -> exactly one "last" block
        // per launch, on every graph replay, with no memset.
        is_last = ((prev + 1u) % TOTAL_BLOCKS) == 0u;
    }
    __syncthreads();

    if (is_last) {
        // 2560 partials = 256 threads x 10, fixed order -> deterministic.
        float s = 0.f;
        #pragma unroll
        for (int r = 0; r < TOTAL_BLOCKS / 256; ++r)
            s += __hip_atomic_load(&part[r * 256 + threadIdx.x],
                                   __ATOMIC_RELAXED, __HIP_MEMORY_SCOPE_AGENT);
        s = wave_reduce_dpp(s);
        if (lane == 63) bsum[wave] = s;
        __syncthreads();
        if (threadIdx.x == 0)
            out[0] = (bsum[0] + bsum[1]) + (bsum[2] + bsum[3]);
    }
}

extern "C" void kernel_launch(void* const* d_in, const int* in_sizes, int n_in,
                              void* d_out, int out_size, void* d_ws, size_t ws_size,
                              hipStream_t stream) {
    const float* y_pred = (const float*)d_in[0];   // [131072, 64]
    const float* y_feat = (const float*)d_in[1];   // [131072, 512]
    const float* y_true = (const float*)d_in[2];   // [128, 1024, 64]
    float* out = (float*)d_out;
    float* ws  = (float*)d_ws;

    fused_kernel<<<TOTAL_BLOCKS, 256, 0, stream>>>(y_feat, y_pred, y_true, ws, out);
}

// Round 10
// 55.446 us; speedup vs baseline: 1.1068x; 1.1068x over previous
//
#include <hip/hip_runtime.h>

// Problem constants: N=131072, D=512, C=64, CHUNK=8
#define NC          8388608     // N * C
#define NCHUNK      16384       // N / 8
#define ALPHA       0.1f
#define FEAT_BLOCKS 2048        // 8192 waves, exactly 2 chunks per wave
#define MSE_BLOCKS  512         // exactly 16 float4 iters per thread
#define TOTAL_BLOCKS (FEAT_BLOCKS + MSE_BLOCKS)   // 2560 = 10 * 256

typedef float floatx4 __attribute__((ext_vector_type(4)));  // native vector for nt builtin

// Single v_add_f32 with DPP modifier (rocPRIM wave64 reduce pattern).
template<int ctrl, int rmask>
__device__ __forceinline__ float dpp_add(float v) {
    int t = __builtin_amdgcn_update_dpp(0, __float_as_int(v), ctrl, rmask, 0xf, true);
    return v + __int_as_float(t);
}

// Full 64-lane sum; result valid in lane 63.
__device__ __forceinline__ float wave_reduce_dpp(float v) {
    v = dpp_add<0xB1,  0xf>(v);  // quad_perm xor1
    v = dpp_add<0x4E,  0xf>(v);  // quad_perm xor2
    v = dpp_add<0x141, 0xf>(v);  // row_half_mirror
    v = dpp_add<0x140, 0xf>(v);  // row_mirror
    v = dpp_add<0x142, 0xa>(v);  // row_bcast:15
    v = dpp_add<0x143, 0xc>(v);  // row_bcast:31
    return v;
}

// Non-temporal 16B load: read-once streaming data, don't allocate in cache.
__device__ __forceinline__ floatx4 nt_load4(const float4* p) {
    return __builtin_nontemporal_load((const floatx4*)p);
}

__global__ __launch_bounds__(256) void fused_kernel(const float* __restrict__ feat,
                                                    const float* __restrict__ pred,
                                                    const float* __restrict__ tgt,
                                                    float* __restrict__ part) {
    const int lane = threadIdx.x & 63;
    const int wave = threadIdx.x >> 6;
    __shared__ float bsum[4];

    if (blockIdx.x < FEAT_BLOCKS) {
        // ---- feat_dist: one wave per 8x512 chunk, exactly 2 chunks/wave ----
        const int wid = blockIdx.x * 4 + wave;
        float wacc = 0.f;                     // per-wave accumulator (lane 63)
        #pragma unroll
        for (int s = 0; s < 2; ++s) {
            const int chunk = wid + s * (FEAT_BLOCKS * 4);
            const float4* base = (const float4*)(feat + (size_t)chunk * 8 * 512);
            float a[8][8];
            #pragma unroll
            for (int i = 0; i < 8; ++i) {
                floatx4 v1 = nt_load4(base + i * 128 + lane);
                floatx4 v2 = nt_load4(base + i * 128 + 64 + lane);
                a[i][0] = v1.x; a[i][1] = v1.y; a[i][2] = v1.z; a[i][3] = v1.w;
                a[i][4] = v2.x; a[i][5] = v2.y; a[i][6] = v2.z; a[i][7] = v2.w;
            }

            // 36 upper-tri (incl. diag) per-lane partial dots.
            float p[36];
            #pragma unroll
            for (int i = 0; i < 8; ++i) {
                #pragma unroll
                for (int j = i; j < 8; ++j) {
                    const int idx = 8 * i - (i * (i - 1)) / 2 + (j - i);
                    float s2 = 0.f;
                    #pragma unroll
                    for (int k = 0; k < 8; ++k) s2 = fmaf(a[i][k], a[j][k], s2);
                    p[idx] = s2;
                }
            }

            // Cross-lane sum of all 36 partials, pure-VALU DPP.
            #pragma unroll
            for (int k = 0; k < 36; ++k) p[k] = wave_reduce_dpp(p[k]);

            if (lane == 63) {
                const int diag[8] = {0, 8, 15, 21, 26, 30, 33, 35};
                float rn[8];
                #pragma unroll
                for (int i = 0; i < 8; ++i) rn[i] = rsqrtf(p[diag[i]]);
                float acc = 0.f;
                #pragma unroll
                for (int i = 0; i < 8; ++i) {
                    #pragma unroll
                    for (int j = i + 1; j < 8; ++j) {
                        const int idx = 8 * i - (i * (i - 1)) / 2 + (j - i);
                        acc = fmaf(p[idx], rn[i] * rn[j], acc);
                    }
                }
                wacc += 28.0f - acc;          // sum of (1 - sim) over 28 pairs
            }
        }
        if (lane == 63) bsum[wave] = wacc;
        __syncthreads();
        if (threadIdx.x == 0)
            part[blockIdx.x] = ALPHA * ((bsum[0] + bsum[1]) + (bsum[2] + bsum[3]));
    } else {
        // ---- MSE over 8.4M elements: exactly 16 float4 iters per thread ----
        const int bid = blockIdx.x - FEAT_BLOCKS;
        const float4* p4 = (const float4*)pred;
        const float4* t4 = (const float4*)tgt;
        const int n4 = NC / 4;
        float s = 0.f;
        for (int i = bid * blockDim.x + threadIdx.x; i < n4;
             i += MSE_BLOCKS * blockDim.x) {
            floatx4 a = nt_load4(p4 + i);
            floatx4 b = nt_load4(t4 + i);
            float dx = a.x - b.x, dy = a.y - b.y, dz = a.z - b.z, dw = a.w - b.w;
            s += dx * dx + dy * dy + dz * dz + dw * dw;
        }
        s = wave_reduce_dpp(s);
        if (lane == 63) bsum[wave] = s;
        __syncthreads();
        if (threadIdx.x == 0)
            part[blockIdx.x] = ((bsum[0] + bsum[1]) + (bsum[2] + bsum[3]))
                               * (1.0f / (float)NC);
    }
    // No atomics, no fences: kernel boundary makes part[] visible to final_reduce.
}

// One block: deterministically sum the 2560 per-block partials -> out[0].
__global__ __launch_bounds__(256) void final_reduce(const float* __restrict__ part,
                                                    float* __restrict__ out) {
    const int lane = threadIdx.x & 63;
    const int wave = threadIdx.x >> 6;
    float s = 0.f;
    #pragma unroll
    for (int r = 0; r < TOTAL_BLOCKS / 256; ++r)
        s += part[r * 256 + threadIdx.x];
    s = wave_reduce_dpp(s);
    __shared__ float bsum[4];
    if (lane == 63) bsum[wave] = s;
    __syncthreads();
    if (threadIdx.x == 0)
        out[0] = (bsum[0] + bsum[1]) + (bsum[2] + bsum[3]);
}

extern "C" void kernel_launch(void* const* d_in, const int* in_sizes, int n_in,
                              void* d_out, int out_size, void* d_ws, size_t ws_size,
                              hipStream_t stream) {
    const float* y_pred = (const float*)d_in[0];   // [131072, 64]
    const float* y_feat = (const float*)d_in[1];   // [131072, 512]
    const float* y_true = (const float*)d_in[2];   // [128, 1024, 64]
    float* out = (float*)d_out;
    float* ws  = (float*)d_ws;                     // 2560 partials, fully rewritten each launch

    fused_kernel<<<TOTAL_BLOCKS, 256, 0, stream>>>(y_feat, y_pred, y_true, ws);
    final_reduce<<<1, 256, 0, stream>>>(ws, out);
}